// Round 1
// baseline (2893.215 us; speedup 1.0000x reference)
//
#include <hip/hip_runtime.h>
#include <math.h>

// Problem constants
//   B=4, NB=2048, NA=NC=1024, D=1024, E=8, H=16, HD=64, TOP_K=2
// All-fp32 implementation (no MFMA): top-2 routing makes numerics precision-critical.

// ----------------------------------------------------------------------------
// zero the double[8] load accumulator
__global__ void zero_k(double* p) {
    if (threadIdx.x < 8) p[threadIdx.x] = 0.0;
}

// ----------------------------------------------------------------------------
// sinusoidal time embedding: emb[b][0:512]=sin(t*freq), [512:1024]=cos(t*freq)
// freq computed in double then rounded to match numpy's near-correctly-rounded fp32 exp
__global__ void emb_k(const int* __restrict__ t, float* __restrict__ emb) {
    int b = blockIdx.x;
    int j = threadIdx.x; // 0..511
    float x1 = (float)(-9.210340371976184) * (float)j;  // -log(10000) * j  (fp32, like np)
    float x2 = x1 / 511.0f;
    float freq = (float)exp((double)x2);
    float tf = (float)t[b];
    float arg = tf * freq;                               // fp32 product, like np
    emb[b * 1024 + j]       = (float)sin((double)arg);
    emb[b * 1024 + 512 + j] = (float)cos((double)arg);
}

// ----------------------------------------------------------------------------
// tiny FC for the time-embedding MLP: out[b][n] = dot(in[b], W[n]) + bias[n] (opt silu)
// one wave per output dim (4 dims per wave), grid (B, N/16), block 256
__global__ void te_fc_k(const float* __restrict__ in, const float* __restrict__ W,
                        const float* __restrict__ bias, float* __restrict__ out,
                        int K, int N, int do_silu) {
    int b = blockIdx.x;
    int wv = threadIdx.x >> 6, lane = threadIdx.x & 63;
    const float* inb = in + (size_t)b * K;
    int n0 = blockIdx.y * 16 + wv * 4;
    for (int q = 0; q < 4; q++) {
        int n = n0 + q;
        const float* wr = W + (size_t)n * K;
        float acc = 0.f;
        for (int c = lane * 4; c < K; c += 256) {
            float4 a  = *(const float4*)(inb + c);
            float4 w4 = *(const float4*)(wr + c);
            acc += a.x * w4.x + a.y * w4.y + a.z * w4.z + a.w * w4.w;
        }
#pragma unroll
        for (int off = 1; off < 64; off <<= 1) acc += __shfl_xor(acc, off, 64);
        if (lane == 0) {
            float x = acc + bias[n];
            out[(size_t)b * N + n] = do_silu ? (x / (1.0f + expf(-x))) : x;
        }
    }
}

// ----------------------------------------------------------------------------
// fp32 GEMM: C[orow(r), n] = dot(A[r, :K], W[n, :K]) + bias[n]   (W row-major (N,K))
// 128x128 tile, BK=16, 256 threads, 8x8 frags.
// GATE mode: K=3072 split across 3 A sources (tokens | ctxB | t_emb-per-batch).
// Output row remap: orow = base + (r>>rs)*stride + (r & ((1<<rs)-1))  (identity: rs=13, stride=0)
template<bool GATE, bool RELU>
__global__ __launch_bounds__(256, 2)
void gemm_k(const float* __restrict__ A0, const float* __restrict__ A1,
            const float* __restrict__ A2,
            const float* __restrict__ W, const float* __restrict__ bias,
            float* __restrict__ C, int K,
            int out_rshift, int out_stride, int out_base)
{
    __shared__ float As[16][132];
    __shared__ float Bs[16][132];
    const int tid = threadIdx.x;
    const int tx = tid & 15, ty = tid >> 4;
    const int row0 = blockIdx.x * 128;
    const int col0 = blockIdx.y * 128;
    float acc[8][8];
#pragma unroll
    for (int i = 0; i < 8; i++)
#pragma unroll
        for (int j = 0; j < 8; j++) acc[i][j] = 0.f;

    for (int kk = 0; kk < K; kk += 16) {
        __syncthreads();
        const float* Asel = A0;
        int colbase = kk;
        int seg = 0;
        if (GATE) {
            seg = kk >> 10;
            Asel = (seg == 0) ? A0 : ((seg == 1) ? A1 : A2);
            colbase = kk & 1023;
        }
#pragma unroll
        for (int tp = 0; tp < 2; tp++) {
            int idx = tid + tp * 256;    // 0..511
            int m  = idx >> 2;           // 0..127
            int k4 = (idx & 3) * 4;
            int r = row0 + m;
            int arow = r;
            if (GATE && seg == 2) arow = r >> 11;  // t_emb: one row per batch
            float4 v = *(const float4*)(Asel + (size_t)arow * 1024 + colbase + k4);
            As[k4 + 0][m] = v.x; As[k4 + 1][m] = v.y;
            As[k4 + 2][m] = v.z; As[k4 + 3][m] = v.w;
            float4 wv = *(const float4*)(W + (size_t)(col0 + m) * K + kk + k4);
            Bs[k4 + 0][m] = wv.x; Bs[k4 + 1][m] = wv.y;
            Bs[k4 + 2][m] = wv.z; Bs[k4 + 3][m] = wv.w;
        }
        __syncthreads();
#pragma unroll
        for (int k = 0; k < 16; k++) {
            float4 a0 = *(const float4*)&As[k][ty * 8];
            float4 a1 = *(const float4*)&As[k][ty * 8 + 4];
            float4 b0 = *(const float4*)&Bs[k][tx * 8];
            float4 b1 = *(const float4*)&Bs[k][tx * 8 + 4];
            float av[8] = {a0.x, a0.y, a0.z, a0.w, a1.x, a1.y, a1.z, a1.w};
            float bv[8] = {b0.x, b0.y, b0.z, b0.w, b1.x, b1.y, b1.z, b1.w};
#pragma unroll
            for (int i = 0; i < 8; i++)
#pragma unroll
                for (int j = 0; j < 8; j++)
                    acc[i][j] += av[i] * bv[j];
        }
    }
#pragma unroll
    for (int i = 0; i < 8; i++) {
        int rr = row0 + ty * 8 + i;
        int orow = out_base + (rr >> out_rshift) * out_stride + (rr & ((1 << out_rshift) - 1));
        float* crow = C + (size_t)orow * 1024 + col0 + tx * 8;
#pragma unroll
        for (int j = 0; j < 8; j += 4) {
            float4 v;
            v.x = acc[i][j + 0] + bias[col0 + tx * 8 + j + 0];
            v.y = acc[i][j + 1] + bias[col0 + tx * 8 + j + 1];
            v.z = acc[i][j + 2] + bias[col0 + tx * 8 + j + 2];
            v.w = acc[i][j + 3] + bias[col0 + tx * 8 + j + 3];
            if (RELU) {
                v.x = fmaxf(v.x, 0.f); v.y = fmaxf(v.y, 0.f);
                v.z = fmaxf(v.z, 0.f); v.w = fmaxf(v.w, 0.f);
            }
            *(float4*)(crow + j) = v;
        }
    }
}

// ----------------------------------------------------------------------------
// flash-style fp32 attention, one (b,h,q-tile) per block; HD=64, S=2048, scale=0.125
__global__ __launch_bounds__(256, 2)
void attn_k(const float* __restrict__ Q, const float* __restrict__ Kb,
            const float* __restrict__ Vb, float* __restrict__ O)
{
    __shared__ float Qs[64][68];   // [d][row]
    __shared__ float Ks[64][68];   // [d][col]
    __shared__ float Ps[64][68];   // [col][row]
    __shared__ float Vs[64][72];   // [krow][d]
    const int tid = threadIdx.x;
    const int tx = tid & 15, ty = tid >> 4;
    const int bh = blockIdx.x;            // 0..63
    const int b = bh >> 4, h = bh & 15;
    const int q0 = blockIdx.y * 64;
    const size_t qbase  = ((size_t)(b * 2048 + q0)) * 1024 + h * 64;
    const size_t kvbase = ((size_t)(b * 2048)) * 1024 + h * 64;

#pragma unroll
    for (int tp = 0; tp < 4; tp++) {
        int idx = tid + tp * 256;
        int m = idx >> 4;                 // 0..63
        int d4 = (idx & 15) * 4;
        float4 v = *(const float4*)(Q + qbase + (size_t)m * 1024 + d4);
        Qs[d4 + 0][m] = v.x; Qs[d4 + 1][m] = v.y;
        Qs[d4 + 2][m] = v.z; Qs[d4 + 3][m] = v.w;
    }
    float o[4][4];
    float mrow[4], lrow[4];
#pragma unroll
    for (int i = 0; i < 4; i++) {
        mrow[i] = -INFINITY; lrow[i] = 0.f;
#pragma unroll
        for (int j = 0; j < 4; j++) o[i][j] = 0.f;
    }
    for (int kt = 0; kt < 32; kt++) {
        __syncthreads();
#pragma unroll
        for (int tp = 0; tp < 4; tp++) {
            int idx = tid + tp * 256;
            int m = idx >> 4;
            int d4 = (idx & 15) * 4;
            size_t gofs = kvbase + (size_t)(kt * 64 + m) * 1024 + d4;
            float4 kv = *(const float4*)(Kb + gofs);
            Ks[d4 + 0][m] = kv.x; Ks[d4 + 1][m] = kv.y;
            Ks[d4 + 2][m] = kv.z; Ks[d4 + 3][m] = kv.w;
            float4 vv = *(const float4*)(Vb + gofs);
            *(float4*)&Vs[m][d4] = vv;
        }
        __syncthreads();
        float s[4][4];
#pragma unroll
        for (int i = 0; i < 4; i++)
#pragma unroll
            for (int j = 0; j < 4; j++) s[i][j] = 0.f;
        for (int d = 0; d < 64; d++) {
            float4 qf = *(const float4*)&Qs[d][ty * 4];
            float4 kf = *(const float4*)&Ks[d][tx * 4];
            float qa[4] = {qf.x, qf.y, qf.z, qf.w};
            float ka[4] = {kf.x, kf.y, kf.z, kf.w};
#pragma unroll
            for (int i = 0; i < 4; i++)
#pragma unroll
                for (int j = 0; j < 4; j++)
                    s[i][j] += qa[i] * ka[j];
        }
#pragma unroll
        for (int i = 0; i < 4; i++) {
            float rmax = -INFINITY;
#pragma unroll
            for (int j = 0; j < 4; j++) { s[i][j] *= 0.125f; rmax = fmaxf(rmax, s[i][j]); }
#pragma unroll
            for (int off = 1; off < 16; off <<= 1)
                rmax = fmaxf(rmax, __shfl_xor(rmax, off, 64));
            float mnew = fmaxf(mrow[i], rmax);
            float corr = expf(mrow[i] - mnew);
            float psum = 0.f;
#pragma unroll
            for (int j = 0; j < 4; j++) { float p = expf(s[i][j] - mnew); s[i][j] = p; psum += p; }
#pragma unroll
            for (int off = 1; off < 16; off <<= 1)
                psum += __shfl_xor(psum, off, 64);
            lrow[i] = lrow[i] * corr + psum;
#pragma unroll
            for (int j = 0; j < 4; j++) o[i][j] *= corr;
            mrow[i] = mnew;
#pragma unroll
            for (int j = 0; j < 4; j++) Ps[tx * 4 + j][ty * 4 + i] = s[i][j];
        }
        __syncthreads();
        for (int k2 = 0; k2 < 64; k2++) {
            float4 pf = *(const float4*)&Ps[k2][ty * 4];
            float4 vf = *(const float4*)&Vs[k2][tx * 4];
            float pa[4] = {pf.x, pf.y, pf.z, pf.w};
            float va[4] = {vf.x, vf.y, vf.z, vf.w};
#pragma unroll
            for (int i = 0; i < 4; i++)
#pragma unroll
                for (int j = 0; j < 4; j++)
                    o[i][j] += pa[i] * va[j];
        }
    }
#pragma unroll
    for (int i = 0; i < 4; i++) {
        float invl = 1.0f / lrow[i];
        int r = q0 + ty * 4 + i;
        float* orow = O + ((size_t)(b * 2048 + r)) * 1024 + h * 64 + tx * 4;
        float4 v;
        v.x = o[i][0] * invl; v.y = o[i][1] * invl;
        v.z = o[i][2] * invl; v.w = o[i][3] * invl;
        *(float4*)orow = v;
    }
}

// ----------------------------------------------------------------------------
// layernorm(X + T) * g + b, one block (256 thr) per row of 1024
__global__ __launch_bounds__(256)
void ln_k(const float* __restrict__ X, const float* __restrict__ T,
          const float* __restrict__ g, const float* __restrict__ bta,
          float* __restrict__ out)
{
    __shared__ float red[8];
    int r = blockIdx.x, tid = threadIdx.x;
    size_t base = (size_t)r * 1024 + tid * 4;
    float4 x  = *(const float4*)(X + base);
    float4 tk = *(const float4*)(T + base);
    x.x += tk.x; x.y += tk.y; x.z += tk.z; x.w += tk.w;
    float s = x.x + x.y + x.z + x.w;
#pragma unroll
    for (int off = 1; off < 64; off <<= 1) s += __shfl_xor(s, off, 64);
    int wv = tid >> 6;
    if ((tid & 63) == 0) red[wv] = s;
    __syncthreads();
    float mu = (red[0] + red[1] + red[2] + red[3]) * (1.0f / 1024.0f);
    float dx0 = x.x - mu, dx1 = x.y - mu, dx2 = x.z - mu, dx3 = x.w - mu;
    float ss = dx0 * dx0 + dx1 * dx1 + dx2 * dx2 + dx3 * dx3;
#pragma unroll
    for (int off = 1; off < 64; off <<= 1) ss += __shfl_xor(ss, off, 64);
    if ((tid & 63) == 0) red[4 + wv] = ss;
    __syncthreads();
    float var = (red[4] + red[5] + red[6] + red[7]) * (1.0f / 1024.0f);
    float inv = 1.0f / sqrtf(var + 1e-5f);
    float4 gg = *(const float4*)(g + tid * 4);
    float4 bb = *(const float4*)(bta + tid * 4);
    float4 y;
    y.x = dx0 * inv * gg.x + bb.x;
    y.y = dx1 * inv * gg.y + bb.y;
    y.z = dx2 * inv * gg.z + bb.z;
    y.w = dx3 * inv * gg.w + bb.w;
    *(float4*)(out + base) = y;
}

// ----------------------------------------------------------------------------
// logits[r][e] = dot(hidden[r], W2[e]) + b2[e] + eb[e]; one wave per row
__global__ __launch_bounds__(256)
void logits_k(const float* __restrict__ Hd, const float* __restrict__ W2,
              const float* __restrict__ b2, const float* __restrict__ eb,
              float* __restrict__ Lg)
{
    int gw = (blockIdx.x * 256 + threadIdx.x) >> 6;  // row 0..8191
    int lane = threadIdx.x & 63;
    const float* h = Hd + (size_t)gw * 1024;
    float4 hv[4];
#pragma unroll
    for (int j = 0; j < 4; j++) hv[j] = *(const float4*)(h + j * 256 + lane * 4);
    float res[8];
#pragma unroll
    for (int e = 0; e < 8; e++) {
        const float* w = W2 + (size_t)e * 1024;
        float acc = 0.f;
#pragma unroll
        for (int j = 0; j < 4; j++) {
            float4 w4 = *(const float4*)(w + j * 256 + lane * 4);
            acc += hv[j].x * w4.x + hv[j].y * w4.y + hv[j].z * w4.z + hv[j].w * w4.w;
        }
#pragma unroll
        for (int off = 1; off < 64; off <<= 1) acc += __shfl_xor(acc, off, 64);
        res[e] = acc;
    }
    if (lane < 8) {
        float v = res[0];
#pragma unroll
        for (int e = 1; e < 8; e++) v = (lane == e) ? res[e] : v;
        Lg[(size_t)gw * 8 + lane] = v + b2[lane] + eb[lane];
    }
}

// ----------------------------------------------------------------------------
// full routing epilogue: one thread per token
__global__ __launch_bounds__(256)
void router_k(const float* __restrict__ Lg, const int* __restrict__ t,
              float* __restrict__ outp, double* __restrict__ loadAcc)
{
    __shared__ double wred[4][8];
    int tid = threadIdx.x;
    int r = blockIdx.x * 256 + tid;   // 0..8191
    int b = r >> 11;
    float tn  = (float)t[b] / 1000.0f;
    float tau = 0.5f + 1.5f * tn;
    float p[8];
    float mx = -INFINITY;
#pragma unroll
    for (int e = 0; e < 8; e++) { p[e] = Lg[(size_t)r * 8 + e] / tau; mx = fmaxf(mx, p[e]); }
    float sum = 0.f;
#pragma unroll
    for (int e = 0; e < 8; e++) { p[e] = expf(p[e] - mx); sum += p[e]; }
#pragma unroll
    for (int e = 0; e < 8; e++) p[e] = p[e] / sum;
#pragma unroll
    for (int e = 0; e < 8; e++) p[e] = 0.85f * p[e] + 0.01875f;   // (1-ALPHA)p + ALPHA/E
    float w = 0.1f + 0.1f * tn;
    float shared_p = fmaxf(p[0], w);
    float osum = 0.f;
#pragma unroll
    for (int e = 1; e < 8; e++) osum += p[e];
    float denom_o = fmaxf(osum, 1e-8f);
    float one_m = 1.0f - shared_p;
    p[0] = shared_p;
#pragma unroll
    for (int e = 1; e < 8; e++) p[e] = (p[e] / denom_o) * one_m;  // match np op order
    // top-2, lowest index wins ties
    int i0 = 0; float v0 = p[0];
#pragma unroll
    for (int e = 1; e < 8; e++) if (p[e] > v0) { v0 = p[e]; i0 = e; }
    int i1 = -1; float v1 = -INFINITY;
#pragma unroll
    for (int e = 0; e < 8; e++) if (e != i0 && p[e] > v1) { v1 = p[e]; i1 = e; }
    float cap = 0.5f + 0.1f * tn;
    float dsp[8], capped[8], hr[8];
    float exsum = 0.f, hsum = 0.f;
#pragma unroll
    for (int e = 0; e < 8; e++) {
        float d = ((e == i0) ? v0 : 0.f) + ((e == i1) ? v1 : 0.f);
        float ex = fmaxf(d - cap, 0.f);
        float c = d - ex;
        float h = fmaxf(cap - c, 0.f);
        capped[e] = c; hr[e] = h;
        exsum += ex; hsum += h;
    }
    float hden = fmaxf(hsum, 1e-8f);
    float dsum = 0.f;
#pragma unroll
    for (int e = 0; e < 8; e++) {
        float d = capped[e] + exsum * (hr[e] / hden);
        dsp[e] = d; dsum += d;
    }
    float cden = dsum + 1e-8f;
#pragma unroll
    for (int e = 0; e < 8; e++) {
        outp[(size_t)r * 8 + e] = dsp[e];
        outp[65536 + (size_t)r * 8 + e] = dsp[e] / cden;
    }
    // per-expert load sums (double precision)
    int lane = tid & 63, wv = tid >> 6;
#pragma unroll
    for (int e = 0; e < 8; e++) {
        double s = (double)dsp[e];
#pragma unroll
        for (int off = 1; off < 64; off <<= 1) s += __shfl_xor(s, off, 64);
        if (lane == 0) wred[wv][e] = s;
    }
    __syncthreads();
    if (tid < 8) {
        double s = wred[0][tid] + wred[1][tid] + wred[2][tid] + wred[3][tid];
        atomicAdd(&loadAcc[tid], s);
    }
}

// ----------------------------------------------------------------------------
__global__ void penalty_k(const double* __restrict__ loadAcc, float* __restrict__ outp) {
    if (threadIdx.x == 0) {
        const float thr = (float)(2048.0 / 7.0 * 1.5);  // fair * 1.5
        float pen = 0.f;
#pragma unroll
        for (int e = 1; e < 8; e++) {
            float load = (float)(loadAcc[e] / 4.0);     // mean over B
            float x = fmaxf(load - thr, 0.f);
            pen += x * x;
        }
        outp[131072] = 0.01f * pen;
    }
}

// ----------------------------------------------------------------------------
extern "C" void kernel_launch(void* const* d_in, const int* in_sizes, int n_in,
                              void* d_out, int out_size, void* d_ws, size_t ws_size,
                              hipStream_t stream)
{
    const float* tokens = (const float*)d_in[0];
    const float* outA   = (const float*)d_in[1];
    const float* outC   = (const float*)d_in[2];
    const int*   tt     = (const int*)  d_in[3];
    const float* in_w   = (const float*)d_in[4];
    const float* in_b   = (const float*)d_in[5];
    const float* op_w   = (const float*)d_in[6];
    const float* op_b   = (const float*)d_in[7];
    const float* lng    = (const float*)d_in[8];
    const float* lnb    = (const float*)d_in[9];
    const float* te_w1  = (const float*)d_in[10];
    const float* te_b1  = (const float*)d_in[11];
    const float* te_w2  = (const float*)d_in[12];
    const float* te_b2  = (const float*)d_in[13];
    const float* g_w1   = (const float*)d_in[14];
    const float* g_b1   = (const float*)d_in[15];
    const float* g_w2   = (const float*)d_in[16];
    const float* g_b2   = (const float*)d_in[17];
    const float* e_bias = (const float*)d_in[18];
    float* out = (float*)d_out;

    float* ws = (float*)d_ws;
    const size_t NM = (size_t)8192 * 1024;
    float* bq   = ws;            // q proj -> later gate hidden
    float* bk   = ws + NM;       // k proj -> later ctx_B (post-LN)
    float* bv   = ws + 2 * NM;   // v proj -> later out_proj raw
    float* bo   = ws + 3 * NM;   // attention output
    float* temb   = ws + 4 * NM;        // 4x1024
    float* embb   = temb + 4096;        // 4x1024
    float* hte    = embb + 4096;        // 4x2048
    float* logitsb = hte + 8192;        // 8192x8
    double* loads = (double*)(logitsb + 65536);  // 8 doubles

    zero_k<<<1, 64, 0, stream>>>(loads);
    emb_k<<<4, 512, 0, stream>>>(tt, embb);
    te_fc_k<<<dim3(4, 128), 256, 0, stream>>>(embb, te_w1, te_b1, hte, 1024, 2048, 1);
    te_fc_k<<<dim3(4, 64),  256, 0, stream>>>(hte,  te_w2, te_b2, temb, 2048, 1024, 0);

    // q = tokens @ wq.T + bq
    gemm_k<false, false><<<dim3(64, 8), 256, 0, stream>>>(
        tokens, nullptr, nullptr, in_w, in_b, bq, 1024, 13, 0, 0);
    // k = [output_A; output_C] @ wk.T + bk  (row-remapped into per-batch concat)
    gemm_k<false, false><<<dim3(32, 8), 256, 0, stream>>>(
        outA, nullptr, nullptr, in_w + (size_t)1024 * 1024, in_b + 1024, bk, 1024, 10, 2048, 0);
    gemm_k<false, false><<<dim3(32, 8), 256, 0, stream>>>(
        outC, nullptr, nullptr, in_w + (size_t)1024 * 1024, in_b + 1024, bk, 1024, 10, 2048, 1024);
    // v
    gemm_k<false, false><<<dim3(32, 8), 256, 0, stream>>>(
        outA, nullptr, nullptr, in_w + (size_t)2 * 1024 * 1024, in_b + 2048, bv, 1024, 10, 2048, 0);
    gemm_k<false, false><<<dim3(32, 8), 256, 0, stream>>>(
        outC, nullptr, nullptr, in_w + (size_t)2 * 1024 * 1024, in_b + 2048, bv, 1024, 10, 2048, 1024);

    attn_k<<<dim3(64, 32), 256, 0, stream>>>(bq, bk, bv, bo);

    // out_proj (into bv, free after attention)
    gemm_k<false, false><<<dim3(64, 8), 256, 0, stream>>>(
        bo, nullptr, nullptr, op_w, op_b, bv, 1024, 13, 0, 0);
    // ctx_B = LN(out_proj + tokens) into bk
    ln_k<<<8192, 256, 0, stream>>>(bv, tokens, lng, lnb, bk);
    // gate hidden = relu([tokens | ctx_B | t_emb] @ gate_w1.T + b1) into bq
    gemm_k<true, true><<<dim3(64, 8), 256, 0, stream>>>(
        tokens, bk, temb, g_w1, g_b1, bq, 3072, 13, 0, 0);

    logits_k<<<2048, 256, 0, stream>>>(bq, g_w2, g_b2, e_bias, logitsb);
    router_k<<<32, 256, 0, stream>>>(logitsb, tt, out, loads);
    penalty_k<<<1, 64, 0, stream>>>(loads, out);
}